// Round 1
// baseline (435.154 us; speedup 1.0000x reference)
//
#include <hip/hip_runtime.h>

// Problem constants (fixed by setup_inputs)
#define N_IMG 4
#define E_DIM 16
#define H_DIM 768
#define W_DIM 768
#define P_PIX (H_DIM * W_DIM)   // 589824 pixels per image
#define C_CL 32
#define PAD 17                  // mean table pad (bank = (17*lab+e)%32, bijective in lab)
#define PRIV 33                 // private-histogram stride: bank = (tid+lab)%32

#define DELTA_VAR 0.5f
#define DELTA_DIST 2.0f
#define GAMMA_W 0.001f
#define EPS_F 1e-12f

// Workspace layout (floats):
//   [0,    2048): sums   [N][C][E]
//   [2048, 2176): counts [N][C]
//   [2176, 2304): hinge  [N][C]
#define WS_SUMS 0
#define WS_CNT 2048
#define WS_HINGE 2176
#define WS_TOTAL 2304

// Pass 1 geometry
#define STEPS 32
#define PX_PER_BLOCK 2048                // 64 px/step * 32 steps
#define BLOCKS_X (P_PIX / PX_PER_BLOCK)  // 288

// Pass 2 geometry (decoupled: tiny LDS -> go wide for TLP)
#define PX2 1024                         // 256 threads * 4 px
#define BLOCKS2_X (P_PIX / PX2)          // 576

__device__ __forceinline__ void gatomic_add(float* p, float v) {
#if defined(__HIP_DEVICE_COMPILE__)
  unsafeAtomicAdd(p, v);  // hw global_atomic_add_f32 on gfx950
#else
  atomicAdd(p, v);
#endif
}

// Pass 1: per-cluster sums and counts via per-thread private LDS histograms.
// Thread layout: wave w = tid>>6, lane l = tid&63; e = 4*w + (l>>4); px16 = l&15.
// KEY CHANGE vs prev round: the private-histogram update uses fire-and-forget
// LDS atomics (ds_add_f32, no return). The old `priv[lab] += v` forced the
// compiler to serialize read->wait->add->write per update (labels may alias),
// a ~16k-cycle dependent LDS-latency chain per wave. ds_add_f32 has no
// dependent read, so the loop becomes pure-throughput (global BW bound).
__global__ __launch_bounds__(256) void pass1(const float* __restrict__ input,
                                             const int* __restrict__ target,
                                             float* __restrict__ ws) {
  __shared__ float s_priv[256 * PRIV];  // 33792 B
  __shared__ float s_cntp[16 * PRIV];   // 2112 B (e==0 threads count pixels)
  const int tid = threadIdx.x;
  const int w = tid >> 6, l = tid & 63;
  const int e = (w << 2) + (l >> 4);
  const int px16 = l & 15;

  float* priv = s_priv + tid * PRIV;
#pragma unroll
  for (int i = 0; i < 32; ++i) priv[i] = 0.f;
  if (tid < 16) {
#pragma unroll
    for (int i = 0; i < 32; ++i) s_cntp[tid * PRIV + i] = 0.f;
  }
  __syncthreads();

  const int n = blockIdx.y;
  const float* inp_e = input + ((size_t)n * E_DIM + e) * P_PIX;
  const int* tgt_n = target + (size_t)n * P_PIX;
  const int base = blockIdx.x * PX_PER_BLOCK + px16 * 4;
  float* cpriv = s_cntp + px16 * PRIV;

  // software pipeline: keep the global stream ahead of the LDS updates
  int4 lab = *reinterpret_cast<const int4*>(tgt_n + base);
  float4 v = *reinterpret_cast<const float4*>(inp_e + base);
  for (int s = 0; s < STEPS; ++s) {
    const int4 labc = lab;
    const float4 vc = v;
    if (s + 1 < STEPS) {
      const int p = base + (s + 1) * 64;
      lab = *reinterpret_cast<const int4*>(tgt_n + p);
      v = *reinterpret_cast<const float4*>(inp_e + p);
    }
    // fire-and-forget ds_add_f32: no lgkmcnt-dependent chain
    atomicAdd(&priv[labc.x], vc.x);
    atomicAdd(&priv[labc.y], vc.y);
    atomicAdd(&priv[labc.z], vc.z);
    atomicAdd(&priv[labc.w], vc.w);
    if (tid < 16) {  // e == 0 group covers every pixel exactly once
      atomicAdd(&cpriv[labc.x], 1.f);
      atomicAdd(&cpriv[labc.y], 1.f);
      atomicAdd(&cpriv[labc.z], 1.f);
      atomicAdd(&cpriv[labc.w], 1.f);
    }
  }
  __syncthreads();

  // Block flush: sum the 16 private regions sharing each e, one global atomic.
  float* gsum = ws + WS_SUMS + n * C_CL * E_DIM;
#pragma unroll
  for (int i = tid; i < C_CL * E_DIM; i += 256) {
    const int c = i >> 4, ee = i & 15;
    const int t0 = (ee >> 2) * 64 + (ee & 3) * 16;
    float val = 0.f;
#pragma unroll
    for (int k = 0; k < 16; ++k) val += s_priv[(t0 + k) * PRIV + c];
    gatomic_add(&gsum[i], val);
  }
  if (tid < C_CL) {
    float cnt = 0.f;
#pragma unroll
    for (int k = 0; k < 16; ++k) cnt += s_cntp[k * PRIV + tid];
    gatomic_add(ws + WS_CNT + n * C_CL + tid, cnt);
  }
}

// Pass 2: per-pixel hinge to own-cluster mean.
// KEY CHANGE: dropped the 33 KB private hinge histogram — each thread only
// does 4 hinge accumulations total, so fire-and-forget LDS atomics into a
// single 32-entry table are noise-level cost. LDS drops to ~2.4 KB and the
// grid goes 2x wider (1024 px/block) for latency-hiding TLP.
__global__ __launch_bounds__(256) void pass2(const float* __restrict__ input,
                                             const int* __restrict__ target,
                                             float* __restrict__ ws) {
  __shared__ float s_mean[C_CL * PAD];
  __shared__ float s_hinge[C_CL];
  const int tid = threadIdx.x;
  const int n = blockIdx.y;
  const float* gsum = ws + WS_SUMS + n * C_CL * E_DIM;
  const float* gcnt = ws + WS_CNT + n * C_CL;
  for (int i = tid; i < C_CL * E_DIM; i += 256) {
    const int c = i >> 4, e = i & 15;
    s_mean[c * PAD + e] = gsum[i] / gcnt[c];
  }
  if (tid < C_CL) s_hinge[tid] = 0.f;
  __syncthreads();

  const int p = blockIdx.x * PX2 + tid * 4;
  const float* inp_n = input + (size_t)n * E_DIM * P_PIX;
  const int* tgt_n = target + (size_t)n * P_PIX;

  const int4 lab = *reinterpret_cast<const int4*>(tgt_n + p);
  float ax = 0.f, ay = 0.f, az = 0.f, aw = 0.f;
#pragma unroll
  for (int e = 0; e < E_DIM; ++e) {
    const float4 v =
        *reinterpret_cast<const float4*>(inp_n + (size_t)e * P_PIX + p);
    const float dx = v.x - s_mean[lab.x * PAD + e];
    const float dy = v.y - s_mean[lab.y * PAD + e];
    const float dz = v.z - s_mean[lab.z * PAD + e];
    const float dw = v.w - s_mean[lab.w * PAD + e];
    ax += dx * dx; ay += dy * dy; az += dz * dz; aw += dw * dw;
  }
  float d, h;
  d = sqrtf(fmaxf(ax, EPS_F)); h = fmaxf(d - DELTA_VAR, 0.f);
  atomicAdd(&s_hinge[lab.x], h * h);
  d = sqrtf(fmaxf(ay, EPS_F)); h = fmaxf(d - DELTA_VAR, 0.f);
  atomicAdd(&s_hinge[lab.y], h * h);
  d = sqrtf(fmaxf(az, EPS_F)); h = fmaxf(d - DELTA_VAR, 0.f);
  atomicAdd(&s_hinge[lab.z], h * h);
  d = sqrtf(fmaxf(aw, EPS_F)); h = fmaxf(d - DELTA_VAR, 0.f);
  atomicAdd(&s_hinge[lab.w], h * h);
  __syncthreads();

  if (tid < C_CL) gatomic_add(ws + WS_HINGE + n * C_CL + tid, s_hinge[tid]);
}

// Finalize: variance term + pairwise distance term + regularizer -> scalar.
__global__ __launch_bounds__(256) void finalize(const float* __restrict__ ws,
                                                float* __restrict__ out) {
  __shared__ float s_mean[N_IMG * C_CL * E_DIM];  // 2048 floats
  __shared__ float red[256];
  const int tid = threadIdx.x;
  for (int i = tid; i < N_IMG * C_CL * E_DIM; i += 256) {
    s_mean[i] = ws[WS_SUMS + i] / ws[WS_CNT + (i >> 4)];
  }
  __syncthreads();

  float acc = 0.f;
  for (int i = tid; i < N_IMG * C_CL; i += 256) {
    const float cnt = ws[WS_CNT + i];
    const float h = ws[WS_HINGE + i];
    acc += (h / cnt) * (1.0f / C_CL);
    float nrm2 = 0.f;
    const float* m = s_mean + i * E_DIM;
#pragma unroll
    for (int e = 0; e < E_DIM; ++e) nrm2 += m[e] * m[e];
    acc += GAMMA_W * sqrtf(fmaxf(nrm2, EPS_F)) * (1.0f / C_CL);
  }
  for (int t = tid; t < N_IMG * C_CL * C_CL; t += 256) {
    const int n = t / (C_CL * C_CL);
    const int r = t - n * C_CL * C_CL;
    const int a = r >> 5, b = r & 31;
    if (a != b) {
      const float* ma = s_mean + (n * C_CL + a) * E_DIM;
      const float* mb = s_mean + (n * C_CL + b) * E_DIM;
      float d2 = 0.f;
#pragma unroll
      for (int e = 0; e < E_DIM; ++e) {
        const float df = ma[e] - mb[e];
        d2 += df * df;
      }
      const float dist = sqrtf(fmaxf(d2, EPS_F));
      const float hd = fmaxf(2.f * DELTA_DIST - dist, 0.f);
      acc += hd * hd * (1.0f / (C_CL * (C_CL - 1)));
    }
  }

  red[tid] = acc;
  __syncthreads();
  for (int s = 128; s > 0; s >>= 1) {
    if (tid < s) red[tid] += red[tid + s];
    __syncthreads();
  }
  if (tid == 0) out[0] = red[0] * (1.0f / N_IMG);
}

extern "C" void kernel_launch(void* const* d_in, const int* in_sizes, int n_in,
                              void* d_out, int out_size, void* d_ws,
                              size_t ws_size, hipStream_t stream) {
  const float* input = (const float*)d_in[0];
  const int* target = (const int*)d_in[1];
  float* ws = (float*)d_ws;
  float* out = (float*)d_out;

  hipMemsetAsync(ws, 0, WS_TOTAL * sizeof(float), stream);
  dim3 grid1(BLOCKS_X, N_IMG);
  pass1<<<grid1, 256, 0, stream>>>(input, target, ws);
  dim3 grid2(BLOCKS2_X, N_IMG);
  pass2<<<grid2, 256, 0, stream>>>(input, target, ws);
  finalize<<<1, 256, 0, stream>>>(ws, out);
}

// Round 4
// 344.416 us; speedup vs baseline: 1.2635x; 1.2635x over previous
//
#include <hip/hip_runtime.h>
#include <stdint.h>

// Problem constants (fixed by setup_inputs)
#define N_IMG 4
#define E_DIM 16
#define H_DIM 768
#define W_DIM 768
#define P_PIX (H_DIM * W_DIM)   // 589824 pixels per image
#define C_CL 32
#define PAD 17                  // mean table pad (bank = (17*lab+e)%32, bijective in lab)

#define DELTA_VAR 0.5f
#define DELTA_DIST 2.0f
#define GAMMA_W 0.001f
#define EPS_F 1e-12f

// Workspace layout (floats):
//   [0,    2048): sums   [N][C][E]
//   [2048, 2176): counts [N][C]
//   [2176, 2180): hinge scalar per image [N]
#define WS_SUMS 0
#define WS_CNT 2048
#define WS_HINGE 2176
#define WS_TOTAL 2180

// Pass 1 geometry: 576 blocks/img x 4 waves x 256 px/wave = 589824 px exactly.
#define P1_BLOCKS 576
#define P1_TILES 8              // 8 tiles of 32 px per wave

// Pass 2 geometry
#define PX2 1024                // 256 threads * 4 px
#define BLOCKS2_X (P_PIX / PX2) // 576

using bf16x8 = __attribute__((ext_vector_type(8))) short;
using f32x4 = __attribute__((ext_vector_type(4))) float;

__device__ __forceinline__ void gatomic_add(float* p, float v) {
#if defined(__HIP_DEVICE_COMPILE__)
  unsafeAtomicAdd(p, v);  // hw global_atomic_add_f32 on gfx950
#else
  atomicAdd(p, v);
#endif
}

// Pass 1: segment-sum as MFMA. sums[e][c] = sum_p v[e][p] * onehot[p][c].
// Rocprof (round 1) showed ds_add_f32 costs ~190 cyc/instr (per-lane
// serialized) -> LDS scatter is the wall. Replaced with
// mfma_f32_16x16x32_bf16: A = values (16e x 32px, fp32 split into bf16
// hi+lo for fp32-grade accuracy), B = one-hot of labels (exact in bf16),
// two c-halves. A-slot j and B-slot j are built from the SAME pixel, so
// the HW k-order is irrelevant; only the verified C/D layout
// (col=lane&15, row=(lane>>4)*4+reg) is relied upon. Counts come from one
// extra MFMA with A = all-ones (D row 0 = per-cluster count, exact).
__global__ __launch_bounds__(256) void pass1(const float* __restrict__ input,
                                             const int* __restrict__ target,
                                             float* __restrict__ ws) {
  __shared__ float s_red[4][2][4][64];  // wave, c-half, reg, lane : 8 KB
  __shared__ float s_cnt[4][2][16];
  const int tid = threadIdx.x;
  const int wv = tid >> 6, l = tid & 63;
  const int g = l >> 4, cl = l & 15;  // k-group, and (e-row for A / c-col for B)
  const int n = blockIdx.y;

  const int wid = blockIdx.x * 4 + wv;          // 0..2303 per image
  const int base = wid * (P1_TILES * 32) + g * 8;
  const float* rowp = input + ((size_t)n * E_DIM + cl) * P_PIX;
  const int* tgt = target + (size_t)n * P_PIX;

  f32x4 acc0 = {0.f, 0.f, 0.f, 0.f}, acc1 = {0.f, 0.f, 0.f, 0.f};
  f32x4 cnt0 = {0.f, 0.f, 0.f, 0.f}, cnt1 = {0.f, 0.f, 0.f, 0.f};
  const short ONE = (short)0x3F80;  // bf16 1.0
  const bf16x8 ones = {ONE, ONE, ONE, ONE, ONE, ONE, ONE, ONE};

  // software pipeline, distance 1
  float4 va = *reinterpret_cast<const float4*>(rowp + base);
  float4 vb = *reinterpret_cast<const float4*>(rowp + base + 4);
  int4 la = *reinterpret_cast<const int4*>(tgt + base);
  int4 lb = *reinterpret_cast<const int4*>(tgt + base + 4);

  for (int t = 0; t < P1_TILES; ++t) {
    const float4 cva = va, cvb = vb;
    const int4 cla = la, clb = lb;
    if (t + 1 < P1_TILES) {
      const int p = base + (t + 1) * 32;
      va = *reinterpret_cast<const float4*>(rowp + p);
      vb = *reinterpret_cast<const float4*>(rowp + p + 4);
      la = *reinterpret_cast<const int4*>(tgt + p);
      lb = *reinterpret_cast<const int4*>(tgt + p + 4);
    }

    float ff[8];
    ff[0] = cva.x; ff[1] = cva.y; ff[2] = cva.z; ff[3] = cva.w;
    ff[4] = cvb.x; ff[5] = cvb.y; ff[6] = cvb.z; ff[7] = cvb.w;
    int lab[8];
    lab[0] = cla.x; lab[1] = cla.y; lab[2] = cla.z; lab[3] = cla.w;
    lab[4] = clb.x; lab[5] = clb.y; lab[6] = clb.z; lab[7] = clb.w;

    // A fragments: hi = truncate-to-bf16, lo = bf16(v - hi). Exact split:
    // total representation error ~2^-16 relative.
    union BF { uint32_t w[4]; bf16x8 v; } Ahi, Alo, B0, B1;
#pragma unroll
    for (int q = 0; q < 4; ++q) {
      const uint32_t u0 = __float_as_uint(ff[2 * q]);
      const uint32_t u1 = __float_as_uint(ff[2 * q + 1]);
      Ahi.w[q] = (u0 >> 16) | (u1 & 0xFFFF0000u);
      const float r0 = ff[2 * q] - __uint_as_float(u0 & 0xFFFF0000u);
      const float r1 = ff[2 * q + 1] - __uint_as_float(u1 & 0xFFFF0000u);
      Alo.w[q] = (__float_as_uint(r0) >> 16) | (__float_as_uint(r1) & 0xFFFF0000u);
      // B one-hot fragments for cluster columns cl (half 0) and cl+16 (half 1)
      B0.w[q] = ((lab[2 * q] == cl) ? 0x3F80u : 0u) |
                ((lab[2 * q + 1] == cl) ? 0x3F800000u : 0u);
      B1.w[q] = ((lab[2 * q] == cl + 16) ? 0x3F80u : 0u) |
                ((lab[2 * q + 1] == cl + 16) ? 0x3F800000u : 0u);
    }

    acc0 = __builtin_amdgcn_mfma_f32_16x16x32_bf16(Ahi.v, B0.v, acc0, 0, 0, 0);
    acc0 = __builtin_amdgcn_mfma_f32_16x16x32_bf16(Alo.v, B0.v, acc0, 0, 0, 0);
    acc1 = __builtin_amdgcn_mfma_f32_16x16x32_bf16(Ahi.v, B1.v, acc1, 0, 0, 0);
    acc1 = __builtin_amdgcn_mfma_f32_16x16x32_bf16(Alo.v, B1.v, acc1, 0, 0, 0);
    cnt0 = __builtin_amdgcn_mfma_f32_16x16x32_bf16(ones, B0.v, cnt0, 0, 0, 0);
    cnt1 = __builtin_amdgcn_mfma_f32_16x16x32_bf16(ones, B1.v, cnt1, 0, 0, 0);
  }

  // Block reduction (8 KB LDS) -> one global atomic per (c,e) per block.
#pragma unroll
  for (int r = 0; r < 4; ++r) {
    s_red[wv][0][r][l] = acc0[r];
    s_red[wv][1][r][l] = acc1[r];
  }
  if (g == 0) {  // D row 0 holds the counts
    s_cnt[wv][0][cl] = cnt0[0];
    s_cnt[wv][1][cl] = cnt1[0];
  }
  __syncthreads();

  float* gsum = ws + WS_SUMS + n * C_CL * E_DIM;
#pragma unroll
  for (int i = tid; i < 512; i += 256) {
    const int h = i >> 8, r = (i >> 6) & 3, ll = i & 63;
    const float v = s_red[0][h][r][ll] + s_red[1][h][r][ll] +
                    s_red[2][h][r][ll] + s_red[3][h][r][ll];
    const int c = (ll & 15) + 16 * h;   // D col = lane&15 (+ half offset)
    const int e = (ll >> 4) * 4 + r;    // D row = (lane>>4)*4 + reg
    gatomic_add(&gsum[c * E_DIM + e], v);
  }
  if (tid < C_CL) {
    const int h = tid >> 4, c16 = tid & 15;
    const float v = s_cnt[0][h][c16] + s_cnt[1][h][c16] + s_cnt[2][h][c16] +
                    s_cnt[3][h][c16];
    gatomic_add(ws + WS_CNT + n * C_CL + tid, v);
  }
}

// Pass 2: per-pixel hinge to own-cluster mean.
// KEY CHANGE vs round 1: no per-cluster binning at all. Using counts from
// pass1:  sum_c (sum_{p in c} h_p^2)/cnt_c  ==  sum_p h_p^2 * invcnt[lab_p].
// Each pixel contributes h^2*invcnt[lab] to a single per-image scalar:
// shuffle-reduce per wave, LDS, one global atomic per block. Zero LDS
// atomics (round-1 rocprof: ds_add_f32 ~190cyc/instr was the suspect wall).
// Mean gather is conflict-free: bank=(17*lab+e)%32 bijective in lab.
__global__ __launch_bounds__(256) void pass2(const float* __restrict__ input,
                                             const int* __restrict__ target,
                                             float* __restrict__ ws) {
  __shared__ float s_mean[C_CL * PAD];
  __shared__ float s_icnt[C_CL];
  __shared__ float s_part[4];
  const int tid = threadIdx.x;
  const int n = blockIdx.y;
  const float* gsum = ws + WS_SUMS + n * C_CL * E_DIM;
  const float* gcnt = ws + WS_CNT + n * C_CL;
  for (int i = tid; i < C_CL * E_DIM; i += 256) {
    const int c = i >> 4, e = i & 15;
    s_mean[c * PAD + e] = gsum[i] / gcnt[c];
  }
  if (tid < C_CL) s_icnt[tid] = 1.0f / gcnt[tid];
  __syncthreads();

  const int p = blockIdx.x * PX2 + tid * 4;
  const float* inp_n = input + (size_t)n * E_DIM * P_PIX;
  const int* tgt_n = target + (size_t)n * P_PIX;

  const int4 lab = *reinterpret_cast<const int4*>(tgt_n + p);
  float ax = 0.f, ay = 0.f, az = 0.f, aw = 0.f;
#pragma unroll
  for (int e = 0; e < E_DIM; ++e) {
    const float4 v =
        *reinterpret_cast<const float4*>(inp_n + (size_t)e * P_PIX + p);
    const float dx = v.x - s_mean[lab.x * PAD + e];
    const float dy = v.y - s_mean[lab.y * PAD + e];
    const float dz = v.z - s_mean[lab.z * PAD + e];
    const float dw = v.w - s_mean[lab.w * PAD + e];
    ax += dx * dx; ay += dy * dy; az += dz * dz; aw += dw * dw;
  }
  float d, h, acc = 0.f;
  d = sqrtf(fmaxf(ax, EPS_F)); h = fmaxf(d - DELTA_VAR, 0.f);
  acc += h * h * s_icnt[lab.x];
  d = sqrtf(fmaxf(ay, EPS_F)); h = fmaxf(d - DELTA_VAR, 0.f);
  acc += h * h * s_icnt[lab.y];
  d = sqrtf(fmaxf(az, EPS_F)); h = fmaxf(d - DELTA_VAR, 0.f);
  acc += h * h * s_icnt[lab.z];
  d = sqrtf(fmaxf(aw, EPS_F)); h = fmaxf(d - DELTA_VAR, 0.f);
  acc += h * h * s_icnt[lab.w];

  // wave shuffle-reduce -> per-wave partial -> one global atomic per block
#pragma unroll
  for (int off = 32; off > 0; off >>= 1) acc += __shfl_down(acc, off);
  if ((tid & 63) == 0) s_part[tid >> 6] = acc;
  __syncthreads();
  if (tid == 0) {
    gatomic_add(ws + WS_HINGE + n,
                s_part[0] + s_part[1] + s_part[2] + s_part[3]);
  }
}

// Finalize: variance term + pairwise distance term + regularizer -> scalar.
__global__ __launch_bounds__(256) void finalize(const float* __restrict__ ws,
                                                float* __restrict__ out) {
  __shared__ float s_mean[N_IMG * C_CL * E_DIM];  // 2048 floats
  __shared__ float red[256];
  const int tid = threadIdx.x;
  for (int i = tid; i < N_IMG * C_CL * E_DIM; i += 256) {
    s_mean[i] = ws[WS_SUMS + i] / ws[WS_CNT + (i >> 4)];
  }
  __syncthreads();

  float acc = 0.f;
  // variance term: per-image scalar already = sum_p h^2*invcnt; apply 1/C
  if (tid < N_IMG) acc += ws[WS_HINGE + tid] * (1.0f / C_CL);
  // regularizer over all (n,c) means
  for (int i = tid; i < N_IMG * C_CL; i += 256) {
    float nrm2 = 0.f;
    const float* m = s_mean + i * E_DIM;
#pragma unroll
    for (int e = 0; e < E_DIM; ++e) nrm2 += m[e] * m[e];
    acc += GAMMA_W * sqrtf(fmaxf(nrm2, EPS_F)) * (1.0f / C_CL);
  }
  for (int t = tid; t < N_IMG * C_CL * C_CL; t += 256) {
    const int n = t / (C_CL * C_CL);
    const int r = t - n * C_CL * C_CL;
    const int a = r >> 5, b = r & 31;
    if (a != b) {
      const float* ma = s_mean + (n * C_CL + a) * E_DIM;
      const float* mb = s_mean + (n * C_CL + b) * E_DIM;
      float d2 = 0.f;
#pragma unroll
      for (int e = 0; e < E_DIM; ++e) {
        const float df = ma[e] - mb[e];
        d2 += df * df;
      }
      const float dist = sqrtf(fmaxf(d2, EPS_F));
      const float hd = fmaxf(2.f * DELTA_DIST - dist, 0.f);
      acc += hd * hd * (1.0f / (C_CL * (C_CL - 1)));
    }
  }

  red[tid] = acc;
  __syncthreads();
  for (int s = 128; s > 0; s >>= 1) {
    if (tid < s) red[tid] += red[tid + s];
    __syncthreads();
  }
  if (tid == 0) out[0] = red[0] * (1.0f / N_IMG);
}

extern "C" void kernel_launch(void* const* d_in, const int* in_sizes, int n_in,
                              void* d_out, int out_size, void* d_ws,
                              size_t ws_size, hipStream_t stream) {
  const float* input = (const float*)d_in[0];
  const int* target = (const int*)d_in[1];
  float* ws = (float*)d_ws;
  float* out = (float*)d_out;

  hipMemsetAsync(ws, 0, WS_TOTAL * sizeof(float), stream);
  dim3 grid1(P1_BLOCKS, N_IMG);
  pass1<<<grid1, 256, 0, stream>>>(input, target, ws);
  dim3 grid2(BLOCKS2_X, N_IMG);
  pass2<<<grid2, 256, 0, stream>>>(input, target, ws);
  finalize<<<1, 256, 0, stream>>>(ws, out);
}

// Round 7
// 259.871 us; speedup vs baseline: 1.6745x; 1.3253x over previous
//
#include <hip/hip_runtime.h>
#include <stdint.h>

// Problem constants (fixed by setup_inputs)
#define N_IMG 4
#define E_DIM 16
#define H_DIM 768
#define W_DIM 768
#define P_PIX (H_DIM * W_DIM)   // 589824 pixels per image
#define C_CL 32
#define PAD 17                  // mean table pad (bank = (17*lab+e)%32, bijective in lab)

#define DELTA_VAR 0.5f
#define DELTA_DIST 2.0f
#define GAMMA_W 0.001f
#define EPS_F 1e-12f

// Workspace layout (floats):
//   [0,    2048): sums   [N][C][E]        (c*16+e)
//   [2048, 2176): counts [N][C]
//   [2176, 4480): pass2 per-block hinge partials [N][BLOCKS2_X] (big/mid path)
//                 (fallback: scalar hinge per image at [2176, 2180))
//   [4480, ...) : pass1 per-block partials [N][576][544]    (big path)
#define WS_SUMS 0
#define WS_CNT 2048
#define WS_HINGE 2176
#define WS_HP 2176
#define WS_PART 4480
#define PART_STRIDE 544   // 512 sums + 32 counts per block
#define NPART_FLOATS (N_IMG * 576 * PART_STRIDE)

// Pass 1 geometry: 576 blocks/img x 4 waves x 256 px/wave = 589824 px exactly.
#define P1_BLOCKS 576
#define P1_TILES 8              // 8 tiles of 32 px per wave

// Pass 2 geometry: fatter blocks amortize the mean-table setup (544 L2-latency
// reads + divisions + barrier) 4x vs the 1024-px blocks.
#define PX2 4096                // 256 threads * 4 px * 4 chunks
#define P2_CHUNKS 4
#define BLOCKS2_X (P_PIX / PX2) // 144

using bf16x8 = __attribute__((ext_vector_type(8))) short;
using f32x4 = __attribute__((ext_vector_type(4))) float;

__device__ __forceinline__ void gatomic_add(float* p, float v) {
#if defined(__HIP_DEVICE_COMPILE__)
  unsafeAtomicAdd(p, v);  // hw global_atomic_add_f32 on gfx950
#else
  atomicAdd(p, v);
#endif
}

// Pass 1: segment-sum as MFMA. sums[e][c] = sum_p v[e][p] * onehot[p][c].
// Inner loop HW-verified (round-4 bench, passed). Round-4 rocprof showed
// WRITE_SIZE 18.7MB vs 4.7MB logical and 91% SIMD stall -> 1.18M
// device-scope atomics into ~36 shared cache lines serialize at the
// coherence point. Flush STORES per-block partials (zero contention);
// reduce1 sums them.
__global__ __launch_bounds__(256) void pass1(const float* __restrict__ input,
                                             const int* __restrict__ target,
                                             float* __restrict__ ws,
                                             int partmode) {
  __shared__ float s_red[4][2][4][64];  // wave, c-half, reg, lane : 8 KB
  __shared__ float s_cnt[4][2][16];
  const int tid = threadIdx.x;
  const int wv = tid >> 6, l = tid & 63;
  const int g = l >> 4, cl = l & 15;  // k-group, and (e-row for A / c-col for B)
  const int n = blockIdx.y;

  const int wid = blockIdx.x * 4 + wv;          // 0..2303 per image
  const int base = wid * (P1_TILES * 32) + g * 8;
  const float* rowp = input + ((size_t)n * E_DIM + cl) * P_PIX;
  const int* tgt = target + (size_t)n * P_PIX;

  f32x4 acc0 = {0.f, 0.f, 0.f, 0.f}, acc1 = {0.f, 0.f, 0.f, 0.f};
  f32x4 cnt0 = {0.f, 0.f, 0.f, 0.f}, cnt1 = {0.f, 0.f, 0.f, 0.f};
  const short ONE = (short)0x3F80;  // bf16 1.0
  const bf16x8 ones = {ONE, ONE, ONE, ONE, ONE, ONE, ONE, ONE};

  // software pipeline, distance 1
  float4 va = *reinterpret_cast<const float4*>(rowp + base);
  float4 vb = *reinterpret_cast<const float4*>(rowp + base + 4);
  int4 la = *reinterpret_cast<const int4*>(tgt + base);
  int4 lb = *reinterpret_cast<const int4*>(tgt + base + 4);

  for (int t = 0; t < P1_TILES; ++t) {
    const float4 cva = va, cvb = vb;
    const int4 cla = la, clb = lb;
    if (t + 1 < P1_TILES) {
      const int p = base + (t + 1) * 32;
      va = *reinterpret_cast<const float4*>(rowp + p);
      vb = *reinterpret_cast<const float4*>(rowp + p + 4);
      la = *reinterpret_cast<const int4*>(tgt + p);
      lb = *reinterpret_cast<const int4*>(tgt + p + 4);
    }

    float ff[8];
    ff[0] = cva.x; ff[1] = cva.y; ff[2] = cva.z; ff[3] = cva.w;
    ff[4] = cvb.x; ff[5] = cvb.y; ff[6] = cvb.z; ff[7] = cvb.w;
    int lab[8];
    lab[0] = cla.x; lab[1] = cla.y; lab[2] = cla.z; lab[3] = cla.w;
    lab[4] = clb.x; lab[5] = clb.y; lab[6] = clb.z; lab[7] = clb.w;

    // A fragments: hi = truncate-to-bf16, lo = bf16(v - hi). Exact split:
    // total representation error ~2^-16 relative.
    union BF { uint32_t w[4]; bf16x8 v; } Ahi, Alo, B0, B1;
#pragma unroll
    for (int q = 0; q < 4; ++q) {
      const uint32_t u0 = __float_as_uint(ff[2 * q]);
      const uint32_t u1 = __float_as_uint(ff[2 * q + 1]);
      Ahi.w[q] = (u0 >> 16) | (u1 & 0xFFFF0000u);
      const float r0 = ff[2 * q] - __uint_as_float(u0 & 0xFFFF0000u);
      const float r1 = ff[2 * q + 1] - __uint_as_float(u1 & 0xFFFF0000u);
      Alo.w[q] = (__float_as_uint(r0) >> 16) | (__float_as_uint(r1) & 0xFFFF0000u);
      // B one-hot fragments for cluster columns cl (half 0) and cl+16 (half 1)
      B0.w[q] = ((lab[2 * q] == cl) ? 0x3F80u : 0u) |
                ((lab[2 * q + 1] == cl) ? 0x3F800000u : 0u);
      B1.w[q] = ((lab[2 * q] == cl + 16) ? 0x3F80u : 0u) |
                ((lab[2 * q + 1] == cl + 16) ? 0x3F800000u : 0u);
    }

    acc0 = __builtin_amdgcn_mfma_f32_16x16x32_bf16(Ahi.v, B0.v, acc0, 0, 0, 0);
    acc0 = __builtin_amdgcn_mfma_f32_16x16x32_bf16(Alo.v, B0.v, acc0, 0, 0, 0);
    acc1 = __builtin_amdgcn_mfma_f32_16x16x32_bf16(Ahi.v, B1.v, acc1, 0, 0, 0);
    acc1 = __builtin_amdgcn_mfma_f32_16x16x32_bf16(Alo.v, B1.v, acc1, 0, 0, 0);
    cnt0 = __builtin_amdgcn_mfma_f32_16x16x32_bf16(ones, B0.v, cnt0, 0, 0, 0);
    cnt1 = __builtin_amdgcn_mfma_f32_16x16x32_bf16(ones, B1.v, cnt1, 0, 0, 0);
  }

  // Block reduction (8 KB LDS).
#pragma unroll
  for (int r = 0; r < 4; ++r) {
    s_red[wv][0][r][l] = acc0[r];
    s_red[wv][1][r][l] = acc1[r];
  }
  if (g == 0) {  // D row 0 holds the counts
    s_cnt[wv][0][cl] = cnt0[0];
    s_cnt[wv][1][cl] = cnt1[0];
  }
  __syncthreads();

  if (partmode) {
    // Contention-free flush: plain stores to this block's private slot.
    float* pbase = ws + WS_PART +
                   (size_t)(n * P1_BLOCKS + blockIdx.x) * PART_STRIDE;
#pragma unroll
    for (int i = tid; i < 512; i += 256) {
      const int h = i >> 8, r = (i >> 6) & 3, ll = i & 63;
      const float v = s_red[0][h][r][ll] + s_red[1][h][r][ll] +
                      s_red[2][h][r][ll] + s_red[3][h][r][ll];
      const int c = (ll & 15) + 16 * h;   // D col = lane&15 (+ half offset)
      const int e = (ll >> 4) * 4 + r;    // D row = (lane>>4)*4 + reg
      pbase[c * E_DIM + e] = v;
    }
    if (tid < C_CL) {
      const int h = tid >> 4, c16 = tid & 15;
      pbase[512 + tid] = s_cnt[0][h][c16] + s_cnt[1][h][c16] +
                         s_cnt[2][h][c16] + s_cnt[3][h][c16];
    }
  } else {
    // Fallback (small ws): original atomic flush (HW-verified).
    float* gsum = ws + WS_SUMS + n * C_CL * E_DIM;
#pragma unroll
    for (int i = tid; i < 512; i += 256) {
      const int h = i >> 8, r = (i >> 6) & 3, ll = i & 63;
      const float v = s_red[0][h][r][ll] + s_red[1][h][r][ll] +
                      s_red[2][h][r][ll] + s_red[3][h][r][ll];
      const int c = (ll & 15) + 16 * h;
      const int e = (ll >> 4) * 4 + r;
      gatomic_add(&gsum[c * E_DIM + e], v);
    }
    if (tid < C_CL) {
      const int h = tid >> 4, c16 = tid & 15;
      const float v = s_cnt[0][h][c16] + s_cnt[1][h][c16] + s_cnt[2][h][c16] +
                      s_cnt[3][h][c16];
      gatomic_add(ws + WS_CNT + n * C_CL + tid, v);
    }
  }
}

// Reduce pass1 partials: sums[n][i] = sum_b part[n][b][i]. grid (17, N_IMG),
// 256 threads = 8 b-subgroups x 32 i-lanes; 17*32 = 544 outputs per image.
__global__ __launch_bounds__(256) void reduce1(float* __restrict__ ws) {
  __shared__ float s[8][32];
  const int tid = threadIdx.x;
  const int bs = tid >> 5, il = tid & 31;
  const int n = blockIdx.y;
  const int i = blockIdx.x * 32 + il;  // [0, 544)
  const float* part = ws + WS_PART + (size_t)n * P1_BLOCKS * PART_STRIDE;
  float acc = 0.f;
#pragma unroll 8
  for (int b = bs; b < P1_BLOCKS; b += 8) acc += part[b * PART_STRIDE + i];
  s[bs][il] = acc;
  __syncthreads();
  if (tid < 32) {
    const int ii = blockIdx.x * 32 + tid;
    float t = s[0][tid] + s[1][tid] + s[2][tid] + s[3][tid] + s[4][tid] +
              s[5][tid] + s[6][tid] + s[7][tid];
    if (ii < 512)
      ws[WS_SUMS + n * 512 + ii] = t;
    else
      ws[WS_CNT + n * C_CL + (ii - 512)] = t;
  }
}

// Pass 2: per-pixel hinge to own-cluster mean.
// sum_c (sum_{p in c} h_p^2)/cnt_c == sum_p h_p^2 * invcnt[lab_p] -> one
// per-image scalar. hmode=1: per-block STORE (no atomics); finalize sums.
// KEY CHANGE vs round 4: 4096 px/block (4 chunks) amortizes the mean-table
// setup 4x; inner chunk body identical to the HW-verified 1024-px version.
__global__ __launch_bounds__(256) void pass2(const float* __restrict__ input,
                                             const int* __restrict__ target,
                                             float* __restrict__ ws,
                                             int hmode) {
  __shared__ float s_mean[C_CL * PAD];
  __shared__ float s_icnt[C_CL];
  __shared__ float s_part[4];
  const int tid = threadIdx.x;
  const int n = blockIdx.y;
  const float* gsum = ws + WS_SUMS + n * C_CL * E_DIM;
  const float* gcnt = ws + WS_CNT + n * C_CL;
  for (int i = tid; i < C_CL * E_DIM; i += 256) {
    const int c = i >> 4, e = i & 15;
    s_mean[c * PAD + e] = gsum[i] / gcnt[c];
  }
  if (tid < C_CL) s_icnt[tid] = 1.0f / gcnt[tid];
  __syncthreads();

  const int base = blockIdx.x * PX2;
  const float* inp_n = input + (size_t)n * E_DIM * P_PIX;
  const int* tgt_n = target + (size_t)n * P_PIX;

  float acc = 0.f;
#pragma unroll
  for (int ch = 0; ch < P2_CHUNKS; ++ch) {
    const int p = base + ch * 1024 + tid * 4;
    const int4 lab = *reinterpret_cast<const int4*>(tgt_n + p);
    float ax = 0.f, ay = 0.f, az = 0.f, aw = 0.f;
#pragma unroll
    for (int e = 0; e < E_DIM; ++e) {
      const float4 v =
          *reinterpret_cast<const float4*>(inp_n + (size_t)e * P_PIX + p);
      const float dx = v.x - s_mean[lab.x * PAD + e];
      const float dy = v.y - s_mean[lab.y * PAD + e];
      const float dz = v.z - s_mean[lab.z * PAD + e];
      const float dw = v.w - s_mean[lab.w * PAD + e];
      ax += dx * dx; ay += dy * dy; az += dz * dz; aw += dw * dw;
    }
    float d, h;
    d = sqrtf(fmaxf(ax, EPS_F)); h = fmaxf(d - DELTA_VAR, 0.f);
    acc += h * h * s_icnt[lab.x];
    d = sqrtf(fmaxf(ay, EPS_F)); h = fmaxf(d - DELTA_VAR, 0.f);
    acc += h * h * s_icnt[lab.y];
    d = sqrtf(fmaxf(az, EPS_F)); h = fmaxf(d - DELTA_VAR, 0.f);
    acc += h * h * s_icnt[lab.z];
    d = sqrtf(fmaxf(aw, EPS_F)); h = fmaxf(d - DELTA_VAR, 0.f);
    acc += h * h * s_icnt[lab.w];
  }

  // wave shuffle-reduce -> per-wave partial -> one store (or atomic) per block
#pragma unroll
  for (int off = 32; off > 0; off >>= 1) acc += __shfl_down(acc, off);
  if ((tid & 63) == 0) s_part[tid >> 6] = acc;
  __syncthreads();
  if (tid == 0) {
    const float total = s_part[0] + s_part[1] + s_part[2] + s_part[3];
    if (hmode)
      ws[WS_HP + n * BLOCKS2_X + blockIdx.x] = total;
    else
      gatomic_add(ws + WS_HINGE + n, total);
  }
}

// Finalize: variance term + pairwise distance term + regularizer -> scalar.
__global__ __launch_bounds__(256) void finalize(const float* __restrict__ ws,
                                                float* __restrict__ out,
                                                int hmode) {
  __shared__ float s_mean[N_IMG * C_CL * E_DIM];  // 2048 floats
  __shared__ float red[256];
  const int tid = threadIdx.x;
  for (int i = tid; i < N_IMG * C_CL * E_DIM; i += 256) {
    s_mean[i] = ws[WS_SUMS + i] / ws[WS_CNT + (i >> 4)];
  }
  __syncthreads();

  float acc = 0.f;
  // variance term (already sum_p h^2*invcnt per image); apply 1/C
  if (hmode) {
    for (int i = tid; i < N_IMG * BLOCKS2_X; i += 256)
      acc += ws[WS_HP + i] * (1.0f / C_CL);
  } else {
    if (tid < N_IMG) acc += ws[WS_HINGE + tid] * (1.0f / C_CL);
  }
  // regularizer over all (n,c) means
  for (int i = tid; i < N_IMG * C_CL; i += 256) {
    float nrm2 = 0.f;
    const float* m = s_mean + i * E_DIM;
#pragma unroll
    for (int e = 0; e < E_DIM; ++e) nrm2 += m[e] * m[e];
    acc += GAMMA_W * sqrtf(fmaxf(nrm2, EPS_F)) * (1.0f / C_CL);
  }
  for (int t = tid; t < N_IMG * C_CL * C_CL; t += 256) {
    const int n = t / (C_CL * C_CL);
    const int r = t - n * C_CL * C_CL;
    const int a = r >> 5, b = r & 31;
    if (a != b) {
      const float* ma = s_mean + (n * C_CL + a) * E_DIM;
      const float* mb = s_mean + (n * C_CL + b) * E_DIM;
      float d2 = 0.f;
#pragma unroll
      for (int e = 0; e < E_DIM; ++e) {
        const float df = ma[e] - mb[e];
        d2 += df * df;
      }
      const float dist = sqrtf(fmaxf(d2, EPS_F));
      const float hd = fmaxf(2.f * DELTA_DIST - dist, 0.f);
      acc += hd * hd * (1.0f / (C_CL * (C_CL - 1)));
    }
  }

  red[tid] = acc;
  __syncthreads();
  for (int s = 128; s > 0; s >>= 1) {
    if (tid < s) red[tid] += red[tid + s];
    __syncthreads();
  }
  if (tid == 0) out[0] = red[0] * (1.0f / N_IMG);
}

extern "C" void kernel_launch(void* const* d_in, const int* in_sizes, int n_in,
                              void* d_out, int out_size, void* d_ws,
                              size_t ws_size, hipStream_t stream) {
  const float* input = (const float*)d_in[0];
  const int* target = (const int*)d_in[1];
  float* ws = (float*)d_ws;
  float* out = (float*)d_out;

  const bool big_ws = ws_size >= (size_t)(WS_PART + NPART_FLOATS) * 4;
  const bool mid_ws = ws_size >= (size_t)WS_PART * 4;
  const int partmode = big_ws ? 1 : 0;
  const int hmode = mid_ws ? 1 : 0;

  if (!big_ws || !mid_ws) {
    hipMemsetAsync(ws, 0, 2180 * sizeof(float), stream);
  }
  dim3 grid1(P1_BLOCKS, N_IMG);
  pass1<<<grid1, 256, 0, stream>>>(input, target, ws, partmode);
  if (big_ws) {
    dim3 gridr(17, N_IMG);
    reduce1<<<gridr, 256, 0, stream>>>(ws);
  }
  dim3 grid2(BLOCKS2_X, N_IMG);
  pass2<<<grid2, 256, 0, stream>>>(input, target, ws, hmode);
  finalize<<<1, 256, 0, stream>>>(ws, out, hmode);
}

// Round 10
// 259.357 us; speedup vs baseline: 1.6778x; 1.0020x over previous
//
#include <hip/hip_runtime.h>
#include <stdint.h>

// Problem constants (fixed by setup_inputs)
#define N_IMG 4
#define E_DIM 16
#define H_DIM 768
#define W_DIM 768
#define P_PIX (H_DIM * W_DIM)   // 589824 pixels per image
#define C_CL 32
#define PAD2 20                 // pass2 mean row stride (floats): 80B, 16B-aligned,
                                // b128 start bank (20c)%32 spreads over all 32 banks

#define DELTA_VAR 0.5f
#define DELTA_DIST 2.0f
#define GAMMA_W 0.001f
#define EPS_F 1e-12f

// Workspace layout (floats):
//   [0,    2048): sums   [N][C][E]        (c*16+e)
//   [2048, 2176): counts [N][C]
//   [2176, 4480): pass2 per-block hinge partials [N][BLOCKS2_X] (big/mid path)
//                 (fallback: scalar hinge per image at [2176, 2180))
//   [4480, ...) : pass1 per-block partials [N][576][544]    (big path)
#define WS_SUMS 0
#define WS_CNT 2048
#define WS_HINGE 2176
#define WS_HP 2176
#define WS_PART 4480
#define PART_STRIDE 544   // 512 sums + 32 counts per block
#define NPART_FLOATS (N_IMG * 576 * PART_STRIDE)

// Pass 1 geometry: 576 blocks/img x 4 waves x 256 px/wave = 589824 px exactly.
#define P1_BLOCKS 576
#define P1_TILES 8              // 8 tiles of 32 px per wave

// Pass 2 geometry: 2048 px/block = 2 chunks. Round-6's 4096 left only
// 2.25 blocks/CU (9 waves/CU) -> latency-bound. 1152 blocks = 18 waves/CU.
#define PX2 2048
#define P2_CHUNKS 2
#define BLOCKS2_X (P_PIX / PX2) // 288

using bf16x8 = __attribute__((ext_vector_type(8))) short;
using f32x4 = __attribute__((ext_vector_type(4))) float;

__device__ __forceinline__ void gatomic_add(float* p, float v) {
#if defined(__HIP_DEVICE_COMPILE__)
  unsafeAtomicAdd(p, v);  // hw global_atomic_add_f32 on gfx950
#else
  atomicAdd(p, v);
#endif
}

// Pass 1: segment-sum as MFMA. sums[e][c] = sum_p v[e][p] * onehot[p][c].
// HW-verified (rounds 4/7, passed). Store-flush of per-block partials
// (round-4 rocprof: 1.18M device-scope atomics into ~36 lines serialized at
// the coherence point; WRITE_SIZE 18.7MB vs 4.7MB logical).
__global__ __launch_bounds__(256) void pass1(const float* __restrict__ input,
                                             const int* __restrict__ target,
                                             float* __restrict__ ws,
                                             int partmode) {
  __shared__ float s_red[4][2][4][64];  // wave, c-half, reg, lane : 8 KB
  __shared__ float s_cnt[4][2][16];
  const int tid = threadIdx.x;
  const int wv = tid >> 6, l = tid & 63;
  const int g = l >> 4, cl = l & 15;  // k-group, and (e-row for A / c-col for B)
  const int n = blockIdx.y;

  const int wid = blockIdx.x * 4 + wv;          // 0..2303 per image
  const int base = wid * (P1_TILES * 32) + g * 8;
  const float* rowp = input + ((size_t)n * E_DIM + cl) * P_PIX;
  const int* tgt = target + (size_t)n * P_PIX;

  f32x4 acc0 = {0.f, 0.f, 0.f, 0.f}, acc1 = {0.f, 0.f, 0.f, 0.f};
  f32x4 cnt0 = {0.f, 0.f, 0.f, 0.f}, cnt1 = {0.f, 0.f, 0.f, 0.f};
  const short ONE = (short)0x3F80;  // bf16 1.0
  const bf16x8 ones = {ONE, ONE, ONE, ONE, ONE, ONE, ONE, ONE};

  // software pipeline, distance 1
  float4 va = *reinterpret_cast<const float4*>(rowp + base);
  float4 vb = *reinterpret_cast<const float4*>(rowp + base + 4);
  int4 la = *reinterpret_cast<const int4*>(tgt + base);
  int4 lb = *reinterpret_cast<const int4*>(tgt + base + 4);

  for (int t = 0; t < P1_TILES; ++t) {
    const float4 cva = va, cvb = vb;
    const int4 cla = la, clb = lb;
    if (t + 1 < P1_TILES) {
      const int p = base + (t + 1) * 32;
      va = *reinterpret_cast<const float4*>(rowp + p);
      vb = *reinterpret_cast<const float4*>(rowp + p + 4);
      la = *reinterpret_cast<const int4*>(tgt + p);
      lb = *reinterpret_cast<const int4*>(tgt + p + 4);
    }

    float ff[8];
    ff[0] = cva.x; ff[1] = cva.y; ff[2] = cva.z; ff[3] = cva.w;
    ff[4] = cvb.x; ff[5] = cvb.y; ff[6] = cvb.z; ff[7] = cvb.w;
    int lab[8];
    lab[0] = cla.x; lab[1] = cla.y; lab[2] = cla.z; lab[3] = cla.w;
    lab[4] = clb.x; lab[5] = clb.y; lab[6] = clb.z; lab[7] = clb.w;

    // A fragments: hi = truncate-to-bf16, lo = bf16(v - hi). Exact split:
    // total representation error ~2^-16 relative.
    union BF { uint32_t w[4]; bf16x8 v; } Ahi, Alo, B0, B1;
#pragma unroll
    for (int q = 0; q < 4; ++q) {
      const uint32_t u0 = __float_as_uint(ff[2 * q]);
      const uint32_t u1 = __float_as_uint(ff[2 * q + 1]);
      Ahi.w[q] = (u0 >> 16) | (u1 & 0xFFFF0000u);
      const float r0 = ff[2 * q] - __uint_as_float(u0 & 0xFFFF0000u);
      const float r1 = ff[2 * q + 1] - __uint_as_float(u1 & 0xFFFF0000u);
      Alo.w[q] = (__float_as_uint(r0) >> 16) | (__float_as_uint(r1) & 0xFFFF0000u);
      // B one-hot fragments for cluster columns cl (half 0) and cl+16 (half 1)
      B0.w[q] = ((lab[2 * q] == cl) ? 0x3F80u : 0u) |
                ((lab[2 * q + 1] == cl) ? 0x3F800000u : 0u);
      B1.w[q] = ((lab[2 * q] == cl + 16) ? 0x3F80u : 0u) |
                ((lab[2 * q + 1] == cl + 16) ? 0x3F800000u : 0u);
    }

    acc0 = __builtin_amdgcn_mfma_f32_16x16x32_bf16(Ahi.v, B0.v, acc0, 0, 0, 0);
    acc0 = __builtin_amdgcn_mfma_f32_16x16x32_bf16(Alo.v, B0.v, acc0, 0, 0, 0);
    acc1 = __builtin_amdgcn_mfma_f32_16x16x32_bf16(Ahi.v, B1.v, acc1, 0, 0, 0);
    acc1 = __builtin_amdgcn_mfma_f32_16x16x32_bf16(Alo.v, B1.v, acc1, 0, 0, 0);
    cnt0 = __builtin_amdgcn_mfma_f32_16x16x32_bf16(ones, B0.v, cnt0, 0, 0, 0);
    cnt1 = __builtin_amdgcn_mfma_f32_16x16x32_bf16(ones, B1.v, cnt1, 0, 0, 0);
  }

  // Block reduction (8 KB LDS).
#pragma unroll
  for (int r = 0; r < 4; ++r) {
    s_red[wv][0][r][l] = acc0[r];
    s_red[wv][1][r][l] = acc1[r];
  }
  if (g == 0) {  // D row 0 holds the counts
    s_cnt[wv][0][cl] = cnt0[0];
    s_cnt[wv][1][cl] = cnt1[0];
  }
  __syncthreads();

  if (partmode) {
    // Contention-free flush: plain stores to this block's private slot.
    float* pbase = ws + WS_PART +
                   (size_t)(n * P1_BLOCKS + blockIdx.x) * PART_STRIDE;
#pragma unroll
    for (int i = tid; i < 512; i += 256) {
      const int h = i >> 8, r = (i >> 6) & 3, ll = i & 63;
      const float v = s_red[0][h][r][ll] + s_red[1][h][r][ll] +
                      s_red[2][h][r][ll] + s_red[3][h][r][ll];
      const int c = (ll & 15) + 16 * h;   // D col = lane&15 (+ half offset)
      const int e = (ll >> 4) * 4 + r;    // D row = (lane>>4)*4 + reg
      pbase[c * E_DIM + e] = v;
    }
    if (tid < C_CL) {
      const int h = tid >> 4, c16 = tid & 15;
      pbase[512 + tid] = s_cnt[0][h][c16] + s_cnt[1][h][c16] +
                         s_cnt[2][h][c16] + s_cnt[3][h][c16];
    }
  } else {
    // Fallback (small ws): original atomic flush (HW-verified).
    float* gsum = ws + WS_SUMS + n * C_CL * E_DIM;
#pragma unroll
    for (int i = tid; i < 512; i += 256) {
      const int h = i >> 8, r = (i >> 6) & 3, ll = i & 63;
      const float v = s_red[0][h][r][ll] + s_red[1][h][r][ll] +
                      s_red[2][h][r][ll] + s_red[3][h][r][ll];
      const int c = (ll & 15) + 16 * h;
      const int e = (ll >> 4) * 4 + r;
      gatomic_add(&gsum[c * E_DIM + e], v);
    }
    if (tid < C_CL) {
      const int h = tid >> 4, c16 = tid & 15;
      const float v = s_cnt[0][h][c16] + s_cnt[1][h][c16] + s_cnt[2][h][c16] +
                      s_cnt[3][h][c16];
      gatomic_add(ws + WS_CNT + n * C_CL + tid, v);
    }
  }
}

// Reduce pass1 partials: sums[n][i] = sum_b part[n][b][i]. grid (17, N_IMG),
// 256 threads = 8 b-subgroups x 32 i-lanes; 17*32 = 544 outputs per image.
__global__ __launch_bounds__(256) void reduce1(float* __restrict__ ws) {
  __shared__ float s[8][32];
  const int tid = threadIdx.x;
  const int bs = tid >> 5, il = tid & 31;
  const int n = blockIdx.y;
  const int i = blockIdx.x * 32 + il;  // [0, 544)
  const float* part = ws + WS_PART + (size_t)n * P1_BLOCKS * PART_STRIDE;
  float acc = 0.f;
#pragma unroll 8
  for (int b = bs; b < P1_BLOCKS; b += 8) acc += part[b * PART_STRIDE + i];
  s[bs][il] = acc;
  __syncthreads();
  if (tid < 32) {
    const int ii = blockIdx.x * 32 + tid;
    float t = s[0][tid] + s[1][tid] + s[2][tid] + s[3][tid] + s[4][tid] +
              s[5][tid] + s[6][tid] + s[7][tid];
    if (ii < 512)
      ws[WS_SUMS + n * 512 + ii] = t;
    else
      ws[WS_CNT + n * C_CL + (ii - 512)] = t;
  }
}

// Pass 2: per-pixel hinge to own-cluster mean.
// sum_c (sum_{p in c} h_p^2)/cnt_c == sum_p h_p^2 * invcnt[lab_p] -> one
// per-image scalar. hmode=1: per-block STORE (no atomics); finalize sums.
// KEY CHANGES vs round 6: (a) PX2 2048 restores TLP (1152 blocks, 18
// waves/CU; 4096 left only 9 waves/CU -> latency-bound); (b) mean table
// [C][PAD2=20] with 16B-aligned rows -> ds_read_b128 fetches 4 e's per
// instr: 64 b32 -> 16 b128 per chunk (~1.9x fewer LDS cycles).
__global__ __launch_bounds__(256) void pass2(const float* __restrict__ input,
                                             const int* __restrict__ target,
                                             float* __restrict__ ws,
                                             int hmode) {
  __shared__ float s_mean[C_CL * PAD2];
  __shared__ float s_icnt[C_CL];
  __shared__ float s_part[4];
  const int tid = threadIdx.x;
  const int n = blockIdx.y;
  const float* gsum = ws + WS_SUMS + n * C_CL * E_DIM;
  const float* gcnt = ws + WS_CNT + n * C_CL;
  for (int i = tid; i < C_CL * E_DIM; i += 256) {
    const int c = i >> 4, e = i & 15;
    s_mean[c * PAD2 + e] = gsum[i] / gcnt[c];
  }
  if (tid < C_CL) s_icnt[tid] = 1.0f / gcnt[tid];
  __syncthreads();

  const int base = blockIdx.x * PX2 + tid * 4;
  const float* inp_n = input + (size_t)n * E_DIM * P_PIX;
  const int* tgt_n = target + (size_t)n * P_PIX;

  // preload both chunks' labels (decouples label->LDS dependency)
  int4 labs[P2_CHUNKS];
#pragma unroll
  for (int ch = 0; ch < P2_CHUNKS; ++ch)
    labs[ch] = *reinterpret_cast<const int4*>(tgt_n + base + ch * 1024);

  float acc = 0.f;
#pragma unroll
  for (int ch = 0; ch < P2_CHUNKS; ++ch) {
    const int p = base + ch * 1024;
    const int4 lab = labs[ch];
    const float4* mx = reinterpret_cast<const float4*>(s_mean + lab.x * PAD2);
    const float4* my = reinterpret_cast<const float4*>(s_mean + lab.y * PAD2);
    const float4* mz = reinterpret_cast<const float4*>(s_mean + lab.z * PAD2);
    const float4* mw = reinterpret_cast<const float4*>(s_mean + lab.w * PAD2);
    float ax = 0.f, ay = 0.f, az = 0.f, aw = 0.f;
#pragma unroll
    for (int eb = 0; eb < 4; ++eb) {  // e-block of 4
      const float4 m_x = mx[eb], m_y = my[eb], m_z = mz[eb], m_w = mw[eb];
      const float4 v0 =
          *reinterpret_cast<const float4*>(inp_n + (size_t)(eb * 4 + 0) * P_PIX + p);
      const float4 v1 =
          *reinterpret_cast<const float4*>(inp_n + (size_t)(eb * 4 + 1) * P_PIX + p);
      const float4 v2 =
          *reinterpret_cast<const float4*>(inp_n + (size_t)(eb * 4 + 2) * P_PIX + p);
      const float4 v3 =
          *reinterpret_cast<const float4*>(inp_n + (size_t)(eb * 4 + 3) * P_PIX + p);
      float d;
      d = v0.x - m_x.x; ax += d * d;
      d = v1.x - m_x.y; ax += d * d;
      d = v2.x - m_x.z; ax += d * d;
      d = v3.x - m_x.w; ax += d * d;
      d = v0.y - m_y.x; ay += d * d;
      d = v1.y - m_y.y; ay += d * d;
      d = v2.y - m_y.z; ay += d * d;
      d = v3.y - m_y.w; ay += d * d;
      d = v0.z - m_z.x; az += d * d;
      d = v1.z - m_z.y; az += d * d;
      d = v2.z - m_z.z; az += d * d;
      d = v3.z - m_z.w; az += d * d;
      d = v0.w - m_w.x; aw += d * d;
      d = v1.w - m_w.y; aw += d * d;
      d = v2.w - m_w.z; aw += d * d;
      d = v3.w - m_w.w; aw += d * d;
    }
    float dd, h;
    dd = sqrtf(fmaxf(ax, EPS_F)); h = fmaxf(dd - DELTA_VAR, 0.f);
    acc += h * h * s_icnt[lab.x];
    dd = sqrtf(fmaxf(ay, EPS_F)); h = fmaxf(dd - DELTA_VAR, 0.f);
    acc += h * h * s_icnt[lab.y];
    dd = sqrtf(fmaxf(az, EPS_F)); h = fmaxf(dd - DELTA_VAR, 0.f);
    acc += h * h * s_icnt[lab.z];
    dd = sqrtf(fmaxf(aw, EPS_F)); h = fmaxf(dd - DELTA_VAR, 0.f);
    acc += h * h * s_icnt[lab.w];
  }

  // wave shuffle-reduce -> per-wave partial -> one store (or atomic) per block
#pragma unroll
  for (int off = 32; off > 0; off >>= 1) acc += __shfl_down(acc, off);
  if ((tid & 63) == 0) s_part[tid >> 6] = acc;
  __syncthreads();
  if (tid == 0) {
    const float total = s_part[0] + s_part[1] + s_part[2] + s_part[3];
    if (hmode)
      ws[WS_HP + n * BLOCKS2_X + blockIdx.x] = total;
    else
      gatomic_add(ws + WS_HINGE + n, total);
  }
}

// Finalize: variance term + pairwise distance term + regularizer -> scalar.
__global__ __launch_bounds__(256) void finalize(const float* __restrict__ ws,
                                                float* __restrict__ out,
                                                int hmode) {
  __shared__ float s_mean[N_IMG * C_CL * E_DIM];  // 2048 floats
  __shared__ float red[256];
  const int tid = threadIdx.x;
  for (int i = tid; i < N_IMG * C_CL * E_DIM; i += 256) {
    s_mean[i] = ws[WS_SUMS + i] / ws[WS_CNT + (i >> 4)];
  }
  __syncthreads();

  float acc = 0.f;
  // variance term (already sum_p h^2*invcnt per image); apply 1/C
  if (hmode) {
    for (int i = tid; i < N_IMG * BLOCKS2_X; i += 256)
      acc += ws[WS_HP + i] * (1.0f / C_CL);
  } else {
    if (tid < N_IMG) acc += ws[WS_HINGE + tid] * (1.0f / C_CL);
  }
  // regularizer over all (n,c) means
  for (int i = tid; i < N_IMG * C_CL; i += 256) {
    float nrm2 = 0.f;
    const float* m = s_mean + i * E_DIM;
#pragma unroll
    for (int e = 0; e < E_DIM; ++e) nrm2 += m[e] * m[e];
    acc += GAMMA_W * sqrtf(fmaxf(nrm2, EPS_F)) * (1.0f / C_CL);
  }
  for (int t = tid; t < N_IMG * C_CL * C_CL; t += 256) {
    const int n = t / (C_CL * C_CL);
    const int r = t - n * C_CL * C_CL;
    const int a = r >> 5, b = r & 31;
    if (a != b) {
      const float* ma = s_mean + (n * C_CL + a) * E_DIM;
      const float* mb = s_mean + (n * C_CL + b) * E_DIM;
      float d2 = 0.f;
#pragma unroll
      for (int e = 0; e < E_DIM; ++e) {
        const float df = ma[e] - mb[e];
        d2 += df * df;
      }
      const float dist = sqrtf(fmaxf(d2, EPS_F));
      const float hd = fmaxf(2.f * DELTA_DIST - dist, 0.f);
      acc += hd * hd * (1.0f / (C_CL * (C_CL - 1)));
    }
  }

  red[tid] = acc;
  __syncthreads();
  for (int s = 128; s > 0; s >>= 1) {
    if (tid < s) red[tid] += red[tid + s];
    __syncthreads();
  }
  if (tid == 0) out[0] = red[0] * (1.0f / N_IMG);
}

extern "C" void kernel_launch(void* const* d_in, const int* in_sizes, int n_in,
                              void* d_out, int out_size, void* d_ws,
                              size_t ws_size, hipStream_t stream) {
  const float* input = (const float*)d_in[0];
  const int* target = (const int*)d_in[1];
  float* ws = (float*)d_ws;
  float* out = (float*)d_out;

  const bool big_ws = ws_size >= (size_t)(WS_PART + NPART_FLOATS) * 4;
  const bool mid_ws = ws_size >= (size_t)WS_PART * 4;
  const int partmode = big_ws ? 1 : 0;
  const int hmode = mid_ws ? 1 : 0;

  if (!big_ws || !mid_ws) {
    hipMemsetAsync(ws, 0, 2180 * sizeof(float), stream);
  }
  dim3 grid1(P1_BLOCKS, N_IMG);
  pass1<<<grid1, 256, 0, stream>>>(input, target, ws, partmode);
  if (big_ws) {
    dim3 gridr(17, N_IMG);
    reduce1<<<gridr, 256, 0, stream>>>(ws);
  }
  dim3 grid2(BLOCKS2_X, N_IMG);
  pass2<<<grid2, 256, 0, stream>>>(input, target, ws, hmode);
  finalize<<<1, 256, 0, stream>>>(ws, out, hmode);
}